// Round 1
// baseline (252.762 us; speedup 1.0000x reference)
//
#include <hip/hip_runtime.h>
#include <hip/hip_bf16.h>
#include <cstdint>
#include <cstddef>

#define HD_B   4
#define SEQ    4096
#define CDIM   768
#define HEADS  12
#define HDIM   64
#define MROWS  (HD_B * SEQ)     // 16384
#define QSCALE 0.125f           // HEAD_DIM^-0.5
#define EPSV   1e-6f

typedef __attribute__((ext_vector_type(8))) short  short8v;  // 8 x bf16 (4 VGPRs)
typedef __attribute__((ext_vector_type(4))) float  f32x4;

__device__ __forceinline__ unsigned short f2b(float f) {
    unsigned int u = __float_as_uint(f);
    u += 0x7FFFu + ((u >> 16) & 1u);   // RNE
    return (unsigned short)(u >> 16);
}
__device__ __forceinline__ float b2f(unsigned short b) {
    return __uint_as_float(((unsigned int)b) << 16);
}
__device__ __forceinline__ float phi_f(float x) {  // elu(x)+1
    return x > 0.f ? x + 1.f : __expf(x);
}

#define GLOAD_LDS16(g, l)                                             \
    __builtin_amdgcn_global_load_lds(                                 \
        (__attribute__((address_space(1))) void*)(void*)(g),          \
        (__attribute__((address_space(3))) void*)(l), 16, 0, 0)

// ---------------------------------------------------------------- converts
__global__ void cvt_f32_bf16(const float* __restrict__ in,
                             unsigned short* __restrict__ out, int n4) {
    int i = blockIdx.x * blockDim.x + threadIdx.x;
    if (i >= n4) return;
    float4 v = reinterpret_cast<const float4*>(in)[i];
    ushort4 o;
    o.x = f2b(v.x); o.y = f2b(v.y); o.z = f2b(v.z); o.w = f2b(v.w);
    reinterpret_cast<ushort4*>(out)[i] = o;
}

// ---------------------------------------------------------------- GEMM
// C[m,n] = sum_k A[m,k] * B[n,k]  (B^T form; both K-contiguous, bf16)
// EPI: 0 = phi(SCALE*(acc+b)) -> bf16   (Q)
//      1 = phi(acc+b)         -> bf16   (K)
//      2 = acc+b              -> bf16   (V)
//      3 = acc+b              -> fp32   (out proj)
#define BM  128
#define BN  128
#define BKK 32

template <int EPI>
__global__ __launch_bounds__(256) void gemm_bt(
    const unsigned short* __restrict__ A,
    const unsigned short* __restrict__ Bw,
    const float* __restrict__ bias,
    void* __restrict__ Cout, int M, int N, int K)
{
    __shared__ unsigned short As[BM][BKK];   // 8 KB
    __shared__ unsigned short Bs[BN][BKK];   // 8 KB

    const int tid  = threadIdx.x;
    const int lane = tid & 63;
    const int w    = tid >> 6;        // wave 0..3
    const int wr   = w >> 1;          // wave row 0..1 (64-row subtile)
    const int wc   = w & 1;           // wave col 0..1
    const int brow = blockIdx.x * BM;
    const int bcol = blockIdx.y * BN;

    f32x4 acc[4][4];
#pragma unroll
    for (int i = 0; i < 4; ++i)
#pragma unroll
        for (int j = 0; j < 4; ++j)
            acc[i][j] = (f32x4){0.f, 0.f, 0.f, 0.f};

    // staging geometry: one global_load_lds writes 64 lanes x 16B = 1 KB = 16 LDS rows
    const int lrow = lane >> 2;          // 0..15
    const int lk   = (lane & 3) << 3;    // 0,8,16,24
    const unsigned short* pA = A  + (size_t)(brow + w * 32 + lrow) * K + lk;
    const unsigned short* pB = Bw + (size_t)(bcol + w * 32 + lrow) * K + lk;

    const int fr = lane & 15;
    const int kq = (lane >> 4) << 3;     // 0,8,16,24

    for (int k0 = 0; k0 < K; k0 += BKK) {
        GLOAD_LDS16(pA + k0,                 &As[w * 32][0]);
        GLOAD_LDS16(pA + k0 + (size_t)16 * K, &As[w * 32 + 16][0]);
        GLOAD_LDS16(pB + k0,                 &Bs[w * 32][0]);
        GLOAD_LDS16(pB + k0 + (size_t)16 * K, &Bs[w * 32 + 16][0]);
        asm volatile("s_waitcnt vmcnt(0)" ::: "memory");
        __syncthreads();

        short8v a[4], b[4];
#pragma unroll
        for (int i = 0; i < 4; ++i)
            a[i] = *(const short8v*)(&As[wr * 64 + i * 16 + fr][kq]);
#pragma unroll
        for (int j = 0; j < 4; ++j)
            b[j] = *(const short8v*)(&Bs[wc * 64 + j * 16 + fr][kq]);
#pragma unroll
        for (int i = 0; i < 4; ++i)
#pragma unroll
            for (int j = 0; j < 4; ++j)
                acc[i][j] = __builtin_amdgcn_mfma_f32_16x16x32_bf16(
                    a[i], b[j], acc[i][j], 0, 0, 0);
        __syncthreads();
    }

    // epilogue: C/D layout col = lane&15, row = (lane>>4)*4 + reg
#pragma unroll
    for (int j = 0; j < 4; ++j) {
        const int col = bcol + wc * 64 + j * 16 + fr;
        const float bj = bias[col];
#pragma unroll
        for (int i = 0; i < 4; ++i) {
            const int row0 = brow + wr * 64 + i * 16 + ((lane >> 4) << 2);
#pragma unroll
            for (int r = 0; r < 4; ++r) {
                float v = acc[i][j][r] + bj;
                const size_t idx = (size_t)(row0 + r) * N + col;
                if (EPI == 0)      ((unsigned short*)Cout)[idx] = f2b(phi_f(v * QSCALE));
                else if (EPI == 1) ((unsigned short*)Cout)[idx] = f2b(phi_f(v));
                else if (EPI == 2) ((unsigned short*)Cout)[idx] = f2b(v);
                else               ((float*)Cout)[idx] = v;
            }
        }
    }
}

// ---------------------------------------------------------------- KV state
// part[c][bh][d*64+e] = sum over rows in chunk c of k_phi[n,d]*v[n,e]
// part[c][bh][4096+d] = sum k_phi[n,d]
#define KVCH   128
#define KVITER 2
#define NCHUNK 16   // SEQ / (KVCH*KVITER)

__global__ __launch_bounds__(256) void kv_part(
    const unsigned short* __restrict__ kphi,
    const unsigned short* __restrict__ vmat,
    float* __restrict__ part)
{
    const int bh = blockIdx.y;                // 0..47
    const int b  = bh / HEADS, h = bh % HEADS;
    const int c  = blockIdx.x;                // 0..NCHUNK-1
    __shared__ float Kl[KVCH][HDIM];
    __shared__ float Vl[KVCH][HDIM];
    const int t  = threadIdx.x;
    const int i  = t >> 2;      // kv row d, 0..63
    const int jb = t & 3;       // 16-col group

    float acc[16];
#pragma unroll
    for (int jj = 0; jj < 16; ++jj) acc[jj] = 0.f;
    float ksum = 0.f;

    for (int it = 0; it < KVITER; ++it) {
        const size_t rbase = (size_t)b * SEQ + (size_t)c * (KVCH * KVITER) + it * KVCH;
        __syncthreads();
        for (int l = 0; l < KVCH / 32; ++l) {
            int row = l * 32 + (t >> 3);
            int col = (t & 7) << 3;
            const size_t g = (rbase + row) * CDIM + h * HDIM + col;
            int4 kk = *(const int4*)(kphi + g);
            int4 vv = *(const int4*)(vmat + g);
            const unsigned short* kp = (const unsigned short*)&kk;
            const unsigned short* vp = (const unsigned short*)&vv;
#pragma unroll
            for (int q = 0; q < 8; ++q) {
                Kl[row][col + q] = b2f(kp[q]);
                Vl[row][col + q] = b2f(vp[q]);
            }
        }
        __syncthreads();
        for (int n = 0; n < KVCH; ++n) {
            float kf = Kl[n][i];
            const float4* vr = (const float4*)&Vl[n][jb * 16];
            float4 v0 = vr[0], v1 = vr[1], v2 = vr[2], v3 = vr[3];
            acc[0]  += kf * v0.x; acc[1]  += kf * v0.y; acc[2]  += kf * v0.z; acc[3]  += kf * v0.w;
            acc[4]  += kf * v1.x; acc[5]  += kf * v1.y; acc[6]  += kf * v1.z; acc[7]  += kf * v1.w;
            acc[8]  += kf * v2.x; acc[9]  += kf * v2.y; acc[10] += kf * v2.z; acc[11] += kf * v2.w;
            acc[12] += kf * v3.x; acc[13] += kf * v3.y; acc[14] += kf * v3.z; acc[15] += kf * v3.w;
            ksum += kf;
        }
    }
    float* op = part + ((size_t)c * 48 + bh) * 4160;
#pragma unroll
    for (int jj = 0; jj < 16; ++jj) op[i * 64 + jb * 16 + jj] = acc[jj];
    if (jb == 0) op[4096 + i] = ksum;
}

__global__ void kv_finalize(const float* __restrict__ part, float* __restrict__ kv) {
    int idx = blockIdx.x * 256 + threadIdx.x;
    if (idx >= 48 * 4160) return;
    float s = 0.f;
    for (int c = 0; c < NCHUNK; ++c) s += part[(size_t)c * 48 * 4160 + idx];
    kv[idx] = s;
}

// ---------------------------------------------------------------- apply
// attn[m, h*64+e] = (sum_d qphi[m,h,d]*kv[bh][d,e]) / (sum_d qphi*ksum + eps)
__global__ __launch_bounds__(256) void attn_apply(
    const unsigned short* __restrict__ qphi,
    const float* __restrict__ kv,
    unsigned short* __restrict__ attn)
{
    const int h  = blockIdx.y;
    const int m0 = blockIdx.x * 64;
    const int b  = m0 >> 12;
    const int bh = b * HEADS + h;
    __shared__ float kvs[HDIM][HDIM];
    __shared__ float ksums[HDIM];
    __shared__ unsigned short ql[64][HDIM];
    const int t = threadIdx.x;
    const float* kvp = kv + (size_t)bh * 4160;
#pragma unroll
    for (int it = 0; it < 4; ++it) {
        int e = it * 1024 + t * 4;
        *(float4*)&kvs[e >> 6][e & 63] = *(const float4*)&kvp[e];
    }
    if (t < 64) ksums[t] = kvp[4096 + t];
#pragma unroll
    for (int it = 0; it < 2; ++it) {
        int row = it * 32 + (t >> 3);
        int col = (t & 7) << 3;
        *(int4*)&ql[row][col] =
            *(const int4*)(qphi + (size_t)(m0 + row) * CDIM + h * HDIM + col);
    }
    __syncthreads();

    const int r  = t >> 2;
    const int jb = t & 3;
    float acc[16];
#pragma unroll
    for (int jj = 0; jj < 16; ++jj) acc[jj] = 0.f;
    float z = 0.f;
    for (int q8 = 0; q8 < 8; ++q8) {
        short8v qv = *(const short8v*)&ql[r][q8 * 8];
#pragma unroll
        for (int dd = 0; dd < 8; ++dd) {
            float qd = b2f((unsigned short)qv[dd]);
            int d = q8 * 8 + dd;
            const float4* kr = (const float4*)&kvs[d][jb * 16];
            float4 k0 = kr[0], k1 = kr[1], k2 = kr[2], k3 = kr[3];
            acc[0]  += qd * k0.x; acc[1]  += qd * k0.y; acc[2]  += qd * k0.z; acc[3]  += qd * k0.w;
            acc[4]  += qd * k1.x; acc[5]  += qd * k1.y; acc[6]  += qd * k1.z; acc[7]  += qd * k1.w;
            acc[8]  += qd * k2.x; acc[9]  += qd * k2.y; acc[10] += qd * k2.z; acc[11] += qd * k2.w;
            acc[12] += qd * k3.x; acc[13] += qd * k3.y; acc[14] += qd * k3.z; acc[15] += qd * k3.w;
            z += qd * ksums[d];
        }
    }
    const float inv = 1.f / (z + EPSV);
    unsigned short* op = attn + (size_t)(m0 + r) * CDIM + h * HDIM + jb * 16;
#pragma unroll
    for (int jj = 0; jj < 16; ++jj) op[jj] = f2b(acc[jj] * inv);
}

// ---------------------------------------------------------------- launch
extern "C" void kernel_launch(void* const* d_in, const int* in_sizes, int n_in,
                              void* d_out, int out_size, void* d_ws, size_t ws_size,
                              hipStream_t stream)
{
    const float* x_q  = (const float*)d_in[0];
    const float* x_kv = (const float*)d_in[1];
    const float* Wq   = (const float*)d_in[2];
    const float* bq   = (const float*)d_in[3];
    const float* Wk   = (const float*)d_in[4];
    const float* bk   = (const float*)d_in[5];
    const float* Wv   = (const float*)d_in[6];
    const float* bv   = (const float*)d_in[7];
    const float* Wp   = (const float*)d_in[8];
    const float* bp   = (const float*)d_in[9];
    float* out = (float*)d_out;

    char* ws = (char*)d_ws;
    size_t off = 0;
    auto alloc = [&](size_t bytes) -> char* {
        char* p = ws + off;
        off += (bytes + 255) & ~(size_t)255;
        return p;
    };
    const size_t xbytes = (size_t)MROWS * CDIM * 2;
    const size_t wbytes = (size_t)CDIM * CDIM * 2;
    unsigned short* xq16  = (unsigned short*)alloc(xbytes);
    unsigned short* xkv16 = (unsigned short*)alloc(xbytes);
    unsigned short* wq16  = (unsigned short*)alloc(wbytes);
    unsigned short* wk16  = (unsigned short*)alloc(wbytes);
    unsigned short* wv16  = (unsigned short*)alloc(wbytes);
    unsigned short* wp16  = (unsigned short*)alloc(wbytes);
    unsigned short* qphi  = (unsigned short*)alloc(xbytes);
    unsigned short* kphi  = (unsigned short*)alloc(xbytes);
    unsigned short* v16   = (unsigned short*)alloc(xbytes);
    float* part = (float*)alloc((size_t)NCHUNK * 48 * 4160 * 4);
    float* kvf  = (float*)alloc((size_t)48 * 4160 * 4);
    unsigned short* attn16 = xq16;   // reuse: x_q bf16 dead after Q projection

    const int n4x = MROWS * CDIM / 4;   // 3145728
    const int n4w = CDIM * CDIM / 4;    // 147456
    cvt_f32_bf16<<<n4x / 256, 256, 0, stream>>>(x_q,  xq16,  n4x);
    cvt_f32_bf16<<<n4x / 256, 256, 0, stream>>>(x_kv, xkv16, n4x);
    cvt_f32_bf16<<<n4w / 256, 256, 0, stream>>>(Wq, wq16, n4w);
    cvt_f32_bf16<<<n4w / 256, 256, 0, stream>>>(Wk, wk16, n4w);
    cvt_f32_bf16<<<n4w / 256, 256, 0, stream>>>(Wv, wv16, n4w);
    cvt_f32_bf16<<<n4w / 256, 256, 0, stream>>>(Wp, wp16, n4w);

    dim3 ggrid(MROWS / BM, CDIM / BN);   // (128, 6)
    gemm_bt<0><<<ggrid, 256, 0, stream>>>(xq16,  wq16, bq, (void*)qphi, MROWS, CDIM, CDIM);
    gemm_bt<1><<<ggrid, 256, 0, stream>>>(xkv16, wk16, bk, (void*)kphi, MROWS, CDIM, CDIM);
    gemm_bt<2><<<ggrid, 256, 0, stream>>>(xkv16, wv16, bv, (void*)v16,  MROWS, CDIM, CDIM);

    kv_part<<<dim3(NCHUNK, 48), 256, 0, stream>>>(kphi, v16, part);
    kv_finalize<<<(48 * 4160 + 255) / 256, 256, 0, stream>>>(part, kvf);
    attn_apply<<<dim3(MROWS / 64, HEADS), 256, 0, stream>>>(qphi, kvf, attn16);

    gemm_bt<3><<<ggrid, 256, 0, stream>>>(attn16, wp16, bp, (void*)out, MROWS, CDIM, CDIM);
}